// Round 3
// baseline (70.392 us; speedup 1.0000x reference)
//
#include <hip/hip_runtime.h>
#include <stdint.h>

#define HH 512
#define WW 512
#define PLANE (HH*WW)
#define NCH 20

// dens[] = {1,4,3,2,0,4,4,0,4,3,3,2,3,4}, 4 bits per element
#define DENS_PACK 0x43233404402341ULL
// grav[] = {1,0,1,1,1,0,0,1,0,1,1,1,1,0}, 1 bit per element
#define GRAV_PACK 0x1E9Du

__device__ __forceinline__ int dens_of(int e) {
    return (int)((DENS_PACK >> (e * 4)) & 0xFULL);
}

// ---------------- SWAR helpers (per-byte lanes) ----------------
__device__ __forceinline__ uint32_t eqz4(uint32_t x) {
    uint32_t nz = (x | (x >> 1) | (x >> 2) | (x >> 3)) & 0x01010101u;
    return nz ^ 0x01010101u;
}
__device__ __forceinline__ uint32_t gtb(uint32_t a, uint32_t b) {
    uint32_t t = (a | 0x08080808u) - b;
    return ((t + 0x07070707u) & 0x10101010u) >> 4;
}
__device__ __forceinline__ uint32_t bmask(uint32_t b) {
    uint32_t h = b << 7;
    return (h - (h >> 7)) | h;
}

// ---------------- Kernel 1: pack eid|grav<<4|dens<<5 per cell ----------------
__global__ __launch_bounds__(256) void extract_k(const float* __restrict__ world,
                                                 uint32_t* __restrict__ st) {
    int idx = blockIdx.x * 256 + threadIdx.x;      // 4 cells each
    int b  = idx >> 16;
    int p4 = idx & 0xFFFF;
    const float4* base = (const float4*)(world + (size_t)b * NCH * PLANE) + p4;
    int e0 = 0, e1 = 0, e2 = 0, e3 = 0;
#pragma unroll
    for (int c = 1; c < 14; ++c) {
        float4 v = base[c * (PLANE / 4)];
        if (v.x != 0.0f) e0 = c;
        if (v.y != 0.0f) e1 = c;
        if (v.z != 0.0f) e2 = c;
        if (v.w != 0.0f) e3 = c;
    }
#define PACK(e) ((uint32_t)((e) | (((GRAV_PACK >> (e)) & 1u) << 4) | (dens_of(e) << 5)))
    st[idx] = PACK(e0) | (PACK(e1) << 8) | (PACK(e2) << 16) | (PACK(e3) << 24);
#undef PACK
}

// ---------------- Kernel 2: 9 SWAR passes, write final byte grid ----------------
#define TILE 64
#define HALO_H 9
#define HALO_W 8                 // bytes; word-aligned halo
#define RH (TILE + 2*HALO_H)     // 82 rows
#define RWW 20                   // words per row (80 bytes)
#define RWS 21                   // LDS row stride in words
#define NW (RH*RWW)              // 1640 words

__global__ __launch_bounds__(512) void sim_k(const uint8_t* __restrict__ st_in,
                                             const float* __restrict__ rnd,
                                             uint32_t* __restrict__ st_out) {
    __shared__ uint32_t bufA[RH * RWS];
    __shared__ uint32_t bufB[RH * RWS];
    __shared__ uint32_t aux [RH * RWS];  // per byte: bit0 fall_dir, bit1 did_gravity

    const int tid = threadIdx.x;
    const int b   = blockIdx.z;
    const int h0  = blockIdx.y * TILE;
    const int w0  = blockIdx.x * TILE;
    const uint8_t* stb = st_in + (size_t)b * PLANE;
    const float*   rb  = rnd   + (size_t)b * PLANE;

    // ---- load region (torus wrap; word-aligned) ----
    for (int r = tid; r < NW; r += 512) {
        int i = r / RWW, jw = r - i * RWW;
        int gh  = (h0 + i - HALO_H) & (HH - 1);
        int gwb = (w0 + jw * 4 - HALO_W) & (WW - 1);
        bufA[i * RWS + jw] = *(const uint32_t*)(stb + gh * WW + gwb);
        float4 rv = *(const float4*)(rb + gh * WW + gwb);
        uint32_t aw = 0;
        aw |= (rv.x > 0.5f) ? 0x00000001u : 0u;
        aw |= (rv.y > 0.5f) ? 0x00000100u : 0u;
        aw |= (rv.z > 0.5f) ? 0x00010000u : 0u;
        aw |= (rv.w > 0.5f) ? 0x01000000u : 0u;
        aux[i * RWS + jw] = aw;
    }
    __syncthreads();

    // ---- pass 0: stone support / gravity rewrite (zero-padded at global edges) ----
    for (int r = tid; r < NW; r += 512) {
        int i = r / RWW, jw = r - i * RWW;
        uint32_t s = bufA[i * RWS + jw];
        uint32_t stm = eqz4((s & 0x0F0F0F0Fu) ^ 0x09090909u);
        int im = (i > 0) ? i - 1 : 0;
        int jl = (jw > 0) ? jw - 1 : 0;
        int jr = (jw < RWW - 1) ? jw + 1 : RWW - 1;
        uint32_t wU  = bufA[im * RWS + jw];
        uint32_t wUL = bufA[im * RWS + jl];
        uint32_t wUR = bufA[im * RWS + jr];
        uint32_t upL = (wU << 8) | (wUL >> 24);
        uint32_t upR = (wU >> 8) | (wUR << 24);
        uint32_t stL = eqz4((upL & 0x0F0F0F0Fu) ^ 0x09090909u);
        uint32_t stR = eqz4((upR & 0x0F0F0F0Fu) ^ 0x09090909u);
        int gh  = (h0 + i - HALO_H) & (HH - 1);
        int gwb = (w0 + jw * 4 - HALO_W) & (WW - 1);
        uint32_t rowOK = (gh != 0) ? 0x01010101u : 0u;
        uint32_t okL = 0x01010101u ^ ((gwb == 0)      ? 0x00000001u : 0u);
        uint32_t okR = 0x01010101u ^ ((gwb == WW - 4) ? 0x01000000u : 0u);
        uint32_t supL = stL & okL & rowOK;
        uint32_t supR = stR & okR & rowOK;
        uint32_t g2 = 0x01010101u ^ (supL & supR);
        uint32_t ns = (s & ~0x10101010u) | (g2 << 4);
        bufB[i * RWS + jw] = s ^ ((s ^ ns) & bmask(stm));
    }
    __syncthreads();

    uint32_t* cur = bufB;
    uint32_t* nxt = bufA;

    // ---- passes 1..4: vertical gravity ----
    for (int curr = 0; curr < 4; ++curr) {
        const uint32_t crep = (uint32_t)curr * 0x01010101u;
        for (int r = tid; r < NW; r += 512) {
            int i = r / RWW, jw = r - i * RWW;
            int ia = (i > 0) ? i - 1 : 0;
            int ib = (i < RH - 1) ? i + 1 : RH - 1;
            uint32_t s  = cur[i  * RWS + jw];
            uint32_t sa = cur[ia * RWS + jw];
            uint32_t sb = cur[ib * RWS + jw];
            uint32_t d  = (s  >> 5) & 0x07070707u;
            uint32_t da = (sa >> 5) & 0x07070707u;
            uint32_t db = (sb >> 5) & 0x07070707u;
            uint32_t g  = (s  >> 4) & 0x01010101u;
            uint32_t ga = (sa >> 4) & 0x01010101u;
            uint32_t gb = (sb >> 4) & 0x01010101u;
            uint32_t bel = eqz4(d ^ crep)  & gtb(d, db)  & gb & g;
            uint32_t abv = eqz4(da ^ crep) & gtb(da, d)  & ga & g;
            nxt[i * RWS + jw] = s ^ ((s ^ sb) & bmask(bel)) ^ ((s ^ sa) & bmask(abv));
            aux[i * RWS + jw] |= (abv << 1);
        }
        __syncthreads();
        uint32_t* t = cur; cur = nxt; nxt = t;
    }

    // ---- passes 5..8: diagonal falls (elem,dir) = (2,L),(2,R),(12,L),(12,R) ----
    for (int pass = 0; pass < 4; ++pass) {
        const int  elem = (pass < 2) ? 2 : 12;
        const bool fl   = ((pass & 1) == 0);
        const uint32_t erep = (uint32_t)elem * 0x01010101u;
        for (int r = tid; r < NW; r += 512) {
            int i = r / RWW, jw = r - i * RWW;
            int ia = (i > 0) ? i - 1 : 0;
            int ib = (i < RH - 1) ? i + 1 : RH - 1;
            int jl = (jw > 0) ? jw - 1 : 0;
            int jr = (jw < RWW - 1) ? jw + 1 : RWW - 1;
            uint32_t s   = cur[i * RWS + jw];
            uint32_t wB  = cur[ib * RWS + jw];
            uint32_t wA  = cur[ia * RWS + jw];
            uint32_t aB  = aux[ib * RWS + jw];
            uint32_t aA  = aux[ia * RWS + jw];
            uint32_t sbl, sar, abl, aar;
            if (fl) {
                uint32_t wBL = cur[ib * RWS + jl], wAR = cur[ia * RWS + jr];
                uint32_t aBL = aux[ib * RWS + jl], aAR = aux[ia * RWS + jr];
                sbl = (wB << 8) | (wBL >> 24);
                sar = (wA >> 8) | (wAR << 24);
                abl = (aB << 8) | (aBL >> 24);
                aar = (aA >> 8) | (aAR << 24);
            } else {
                uint32_t wBR = cur[ib * RWS + jr], wAL = cur[ia * RWS + jl];
                uint32_t aBR = aux[ib * RWS + jr], aAL = aux[ia * RWS + jl];
                sbl = (wB >> 8) | (wBR << 24);
                sar = (wA << 8) | (wAL >> 24);
                abl = (aB >> 8) | (aBR << 24);
                aar = (aA << 8) | (aAL >> 24);
            }
            uint32_t ax = aux[i * RWS + jw];
            uint32_t d   = (s   >> 5) & 0x07070707u;
            uint32_t dbl = (sbl >> 5) & 0x07070707u;
            uint32_t dar = (sar >> 5) & 0x07070707u;
            uint32_t g   = (s   >> 4) & 0x01010101u;
            uint32_t gbl = (sbl >> 4) & 0x01010101u;
            uint32_t gar = (sar >> 4) & 0x01010101u;
            uint32_t ndg   = ((~ax)  >> 1) & 0x01010101u;
            uint32_t ndgbl = ((~abl) >> 1) & 0x01010101u;
            uint32_t ndgar = ((~aar) >> 1) & 0x01010101u;
            uint32_t mtc = (fl ? ax  : ~ax)  & 0x01010101u;
            uint32_t mta = (fl ? aar : ~aar) & 0x01010101u;
            uint32_t eqe  = eqz4((s   & 0x0F0F0F0Fu) ^ erep);
            uint32_t eqer = eqz4((sar & 0x0F0F0F0Fu) ^ erep);
            uint32_t bbl = eqe  & ndgbl & ndg & mtc & gtb(d, dbl)  & gbl & g;
            uint32_t bar = eqer & ndgar & ndg & mta & gtb(dar, d)  & gar & g;
            nxt[i * RWS + jw] = s ^ ((s ^ sbl) & bmask(bbl)) ^ ((s ^ sar) & bmask(bar));
        }
        __syncthreads();
        uint32_t* t = cur; cur = nxt; nxt = t;
    }

    // ---- write final core 64x64 bytes (16 words/row) to st_out ----
    uint32_t* ob = st_out + (size_t)b * (PLANE / 4);
    for (int idx = tid; idx < 64 * 16; idx += 512) {
        int row = idx >> 4, cw = idx & 15;
        ob[(size_t)(h0 + row) * (WW / 4) + (w0 / 4) + cw] =
            cur[(HALO_H + row) * RWS + (HALO_W / 4) + cw];
    }
}

// ---------------- Kernel 3: expand byte grid to 20 f32 channels ----------------
__global__ __launch_bounds__(256) void expand_k(const uint32_t* __restrict__ st,
                                                float* __restrict__ out) {
    int idx = blockIdx.x * 256 + threadIdx.x;   // 524288 words total
    uint32_t w = st[idx];
    int b  = idx >> 16;
    int p4 = idx & 0xFFFF;
    float* ob = out + (size_t)b * NCH * PLANE + (size_t)p4 * 4;
    int e0 = w & 15, e1 = (w >> 8) & 15, e2 = (w >> 16) & 15, e3 = (w >> 24) & 15;
#pragma unroll
    for (int c = 0; c < 14; ++c) {
        float4 v;
        v.x = (e0 == c) ? 1.0f : 0.0f;
        v.y = (e1 == c) ? 1.0f : 0.0f;
        v.z = (e2 == c) ? 1.0f : 0.0f;
        v.w = (e3 == c) ? 1.0f : 0.0f;
        *(float4*)(ob + (size_t)c * PLANE) = v;
    }
    {
        float4 v;
        v.x = (float)((w >> 5)  & 7u);
        v.y = (float)((w >> 13) & 7u);
        v.z = (float)((w >> 21) & 7u);
        v.w = (float)((w >> 29) & 7u);
        *(float4*)(ob + (size_t)14 * PLANE) = v;
    }
    {
        float4 v;
        v.x = (float)((w >> 4)  & 1u);
        v.y = (float)((w >> 12) & 1u);
        v.z = (float)((w >> 20) & 1u);
        v.w = (float)((w >> 28) & 1u);
        *(float4*)(ob + (size_t)15 * PLANE) = v;
    }
    float4 z = {0.0f, 0.0f, 0.0f, 0.0f};
#pragma unroll
    for (int c = 16; c < 20; ++c)
        *(float4*)(ob + (size_t)c * PLANE) = z;
}

extern "C" void kernel_launch(void* const* d_in, const int* in_sizes, int n_in,
                              void* d_out, int out_size, void* d_ws, size_t ws_size,
                              hipStream_t stream) {
    const float* world = (const float*)d_in[0];
    const float* rnd   = (const float*)d_in[1];
    float* out = (float*)d_out;
    uint32_t* st  = (uint32_t*)d_ws;                       // 2 MB packed grid (pre-sim)
    uint32_t* st2 = (uint32_t*)((char*)d_ws + 2*1024*1024); // 2 MB packed grid (post-sim)

    extract_k<<<2048, 256, 0, stream>>>(world, st);

    dim3 grid(WW / TILE, HH / TILE, 8);
    sim_k<<<grid, 512, 0, stream>>>((const uint8_t*)st, rnd, st2);

    expand_k<<<2048, 256, 0, stream>>>(st2, out);
}

// Round 4
// 62.898 us; speedup vs baseline: 1.1191x; 1.1191x over previous
//
#include <hip/hip_runtime.h>
#include <stdint.h>

#define HH 512
#define WW 512
#define PLANE (HH*WW)
#define NCH 20

// ---------------- SWAR helpers (per-byte lanes) ----------------
__device__ __forceinline__ uint32_t eqz4(uint32_t x) {
    uint32_t nz = (x | (x >> 1) | (x >> 2) | (x >> 3)) & 0x01010101u;
    return nz ^ 0x01010101u;
}
__device__ __forceinline__ uint32_t gtb(uint32_t a, uint32_t b) {
    uint32_t t = (a | 0x08080808u) - b;
    return ((t + 0x07070707u) & 0x10101010u) >> 4;
}
__device__ __forceinline__ uint32_t bmask(uint32_t b) {
    uint32_t h = b << 7;
    return (h - (h >> 7)) | h;
}

// ---------------- Kernel 1: pack eid|grav<<4|dens<<5 (11-channel read) ----------------
__device__ __forceinline__ uint32_t pack_cell(float d_, float g_,
                                              float c1_, float c5_, float c6_, float c8_,
                                              float c2_, float c9_, float c10_,
                                              float c3_, float c4_) {
    int d = (int)d_;
    int e;
    if (d == 4)      e = (c1_ != 0.f) ? 1 : (c5_ != 0.f) ? 5 : (c6_ != 0.f) ? 6 : (c8_ != 0.f) ? 8 : 13;
    else if (d == 3) e = (c2_ != 0.f) ? 2 : (c9_ != 0.f) ? 9 : (c10_ != 0.f) ? 10 : 12;
    else if (d == 2) e = (c3_ != 0.f) ? 3 : 11;
    else if (d == 1) e = 0;
    else             e = (c4_ != 0.f) ? 4 : 7;
    int g = (g_ != 0.f) ? 1 : 0;
    return (uint32_t)(e | (g << 4) | (d << 5));
}

__global__ __launch_bounds__(256) void extract_k(const float* __restrict__ world,
                                                 uint32_t* __restrict__ st) {
    int idx = blockIdx.x * 256 + threadIdx.x;      // 4 cells each
    int b  = idx >> 16;
    int p4 = idx & 0xFFFF;
    const float4* base = (const float4*)(world + (size_t)b * NCH * PLANE) + p4;
    float4 vD  = base[14 * (PLANE / 4)];
    float4 vG  = base[15 * (PLANE / 4)];
    float4 v1  = base[ 1 * (PLANE / 4)];
    float4 v5  = base[ 5 * (PLANE / 4)];
    float4 v6  = base[ 6 * (PLANE / 4)];
    float4 v8  = base[ 8 * (PLANE / 4)];
    float4 v2  = base[ 2 * (PLANE / 4)];
    float4 v9  = base[ 9 * (PLANE / 4)];
    float4 v10 = base[10 * (PLANE / 4)];
    float4 v3  = base[ 3 * (PLANE / 4)];
    float4 v4  = base[ 4 * (PLANE / 4)];
    uint32_t b0 = pack_cell(vD.x, vG.x, v1.x, v5.x, v6.x, v8.x, v2.x, v9.x, v10.x, v3.x, v4.x);
    uint32_t b1 = pack_cell(vD.y, vG.y, v1.y, v5.y, v6.y, v8.y, v2.y, v9.y, v10.y, v3.y, v4.y);
    uint32_t b2 = pack_cell(vD.z, vG.z, v1.z, v5.z, v6.z, v8.z, v2.z, v9.z, v10.z, v3.z, v4.z);
    uint32_t b3 = pack_cell(vD.w, vG.w, v1.w, v5.w, v6.w, v8.w, v2.w, v9.w, v10.w, v3.w, v4.w);
    st[idx] = b0 | (b1 << 8) | (b2 << 16) | (b3 << 24);
}

// ---------------- Kernel 2: 9 SWAR passes + fused expansion ----------------
#define TILE_R 32
#define TILE_C 64
#define HALO_T 9
#define HALO_B 8
#define HALO_W 8                 // bytes; word-aligned halo
#define RH (TILE_R + HALO_T + HALO_B)  // 49 rows
#define RWW 20                   // words per row (80 bytes)
#define RWS 21                   // LDS row stride in words
#define NW (RH*RWW)              // 980 words

__global__ __launch_bounds__(256, 4) void sim_k(const uint8_t* __restrict__ st_in,
                                                const float* __restrict__ rnd,
                                                float* __restrict__ out) {
    __shared__ uint32_t bufA[RH * RWS];
    __shared__ uint32_t bufB[RH * RWS];
    __shared__ uint32_t aux [RH * RWS];  // per byte: bit0 fall_dir, bit1 did_gravity

    const int tid = threadIdx.x;
    const int b   = blockIdx.z;
    const int h0  = blockIdx.y * TILE_R;
    const int w0  = blockIdx.x * TILE_C;
    const uint8_t* stb = st_in + (size_t)b * PLANE;
    const float*   rb  = rnd   + (size_t)b * PLANE;

    // ---- load region (torus wrap; word-aligned) ----
    for (int r = tid; r < NW; r += 256) {
        int i = r / RWW, jw = r - i * RWW;
        int gh  = (h0 + i - HALO_T) & (HH - 1);
        int gwb = (w0 + jw * 4 - HALO_W) & (WW - 1);
        bufA[i * RWS + jw] = *(const uint32_t*)(stb + gh * WW + gwb);
        float4 rv = *(const float4*)(rb + gh * WW + gwb);
        uint32_t aw = 0;
        aw |= (rv.x > 0.5f) ? 0x00000001u : 0u;
        aw |= (rv.y > 0.5f) ? 0x00000100u : 0u;
        aw |= (rv.z > 0.5f) ? 0x00010000u : 0u;
        aw |= (rv.w > 0.5f) ? 0x01000000u : 0u;
        aux[i * RWS + jw] = aw;
    }
    __syncthreads();

    // ---- pass 0: stone support / gravity rewrite (zero-padded at global edges) ----
    for (int r = tid; r < NW; r += 256) {
        int i = r / RWW, jw = r - i * RWW;
        uint32_t s = bufA[i * RWS + jw];
        uint32_t stm = eqz4((s & 0x0F0F0F0Fu) ^ 0x09090909u);
        int im = (i > 0) ? i - 1 : 0;
        int jl = (jw > 0) ? jw - 1 : 0;
        int jr = (jw < RWW - 1) ? jw + 1 : RWW - 1;
        uint32_t wU  = bufA[im * RWS + jw];
        uint32_t wUL = bufA[im * RWS + jl];
        uint32_t wUR = bufA[im * RWS + jr];
        uint32_t upL = (wU << 8) | (wUL >> 24);
        uint32_t upR = (wU >> 8) | (wUR << 24);
        uint32_t stL = eqz4((upL & 0x0F0F0F0Fu) ^ 0x09090909u);
        uint32_t stR = eqz4((upR & 0x0F0F0F0Fu) ^ 0x09090909u);
        int gh  = (h0 + i - HALO_T) & (HH - 1);
        int gwb = (w0 + jw * 4 - HALO_W) & (WW - 1);
        uint32_t rowOK = (gh != 0) ? 0x01010101u : 0u;
        uint32_t okL = 0x01010101u ^ ((gwb == 0)      ? 0x00000001u : 0u);
        uint32_t okR = 0x01010101u ^ ((gwb == WW - 4) ? 0x01000000u : 0u);
        uint32_t supL = stL & okL & rowOK;
        uint32_t supR = stR & okR & rowOK;
        uint32_t g2 = 0x01010101u ^ (supL & supR);
        uint32_t ns = (s & ~0x10101010u) | (g2 << 4);
        bufB[i * RWS + jw] = s ^ ((s ^ ns) & bmask(stm));
    }
    __syncthreads();

    uint32_t* cur = bufB;
    uint32_t* nxt = bufA;

    // ---- passes 1..4: vertical gravity ----
    for (int curr = 0; curr < 4; ++curr) {
        const uint32_t crep = (uint32_t)curr * 0x01010101u;
        for (int r = tid; r < NW; r += 256) {
            int i = r / RWW, jw = r - i * RWW;
            int ia = (i > 0) ? i - 1 : 0;
            int ib = (i < RH - 1) ? i + 1 : RH - 1;
            uint32_t s  = cur[i  * RWS + jw];
            uint32_t sa = cur[ia * RWS + jw];
            uint32_t sb = cur[ib * RWS + jw];
            uint32_t d  = (s  >> 5) & 0x07070707u;
            uint32_t da = (sa >> 5) & 0x07070707u;
            uint32_t db = (sb >> 5) & 0x07070707u;
            uint32_t g  = (s  >> 4) & 0x01010101u;
            uint32_t ga = (sa >> 4) & 0x01010101u;
            uint32_t gb = (sb >> 4) & 0x01010101u;
            uint32_t bel = eqz4(d ^ crep)  & gtb(d, db)  & gb & g;
            uint32_t abv = eqz4(da ^ crep) & gtb(da, d)  & ga & g;
            nxt[i * RWS + jw] = s ^ ((s ^ sb) & bmask(bel)) ^ ((s ^ sa) & bmask(abv));
            aux[i * RWS + jw] |= (abv << 1);
        }
        __syncthreads();
        uint32_t* t = cur; cur = nxt; nxt = t;
    }

    // ---- passes 5..8: diagonal falls (elem,dir) = (2,L),(2,R),(12,L),(12,R) ----
    for (int pass = 0; pass < 4; ++pass) {
        const int  elem = (pass < 2) ? 2 : 12;
        const bool fl   = ((pass & 1) == 0);
        const uint32_t erep = (uint32_t)elem * 0x01010101u;
        for (int r = tid; r < NW; r += 256) {
            int i = r / RWW, jw = r - i * RWW;
            int ia = (i > 0) ? i - 1 : 0;
            int ib = (i < RH - 1) ? i + 1 : RH - 1;
            int jl = (jw > 0) ? jw - 1 : 0;
            int jr = (jw < RWW - 1) ? jw + 1 : RWW - 1;
            uint32_t s   = cur[i * RWS + jw];
            uint32_t wB  = cur[ib * RWS + jw];
            uint32_t wA  = cur[ia * RWS + jw];
            uint32_t aB  = aux[ib * RWS + jw];
            uint32_t aA  = aux[ia * RWS + jw];
            uint32_t sbl, sar, abl, aar;
            if (fl) {
                uint32_t wBL = cur[ib * RWS + jl], wAR = cur[ia * RWS + jr];
                uint32_t aBL = aux[ib * RWS + jl], aAR = aux[ia * RWS + jr];
                sbl = (wB << 8) | (wBL >> 24);
                sar = (wA >> 8) | (wAR << 24);
                abl = (aB << 8) | (aBL >> 24);
                aar = (aA >> 8) | (aAR << 24);
            } else {
                uint32_t wBR = cur[ib * RWS + jr], wAL = cur[ia * RWS + jl];
                uint32_t aBR = aux[ib * RWS + jr], aAL = aux[ia * RWS + jl];
                sbl = (wB >> 8) | (wBR << 24);
                sar = (wA << 8) | (wAL >> 24);
                abl = (aB >> 8) | (aBR << 24);
                aar = (aA << 8) | (aAL >> 24);
            }
            uint32_t ax = aux[i * RWS + jw];
            uint32_t d   = (s   >> 5) & 0x07070707u;
            uint32_t dbl = (sbl >> 5) & 0x07070707u;
            uint32_t dar = (sar >> 5) & 0x07070707u;
            uint32_t g   = (s   >> 4) & 0x01010101u;
            uint32_t gbl = (sbl >> 4) & 0x01010101u;
            uint32_t gar = (sar >> 4) & 0x01010101u;
            uint32_t ndg   = ((~ax)  >> 1) & 0x01010101u;
            uint32_t ndgbl = ((~abl) >> 1) & 0x01010101u;
            uint32_t ndgar = ((~aar) >> 1) & 0x01010101u;
            uint32_t mtc = (fl ? ax  : ~ax)  & 0x01010101u;
            uint32_t mta = (fl ? aar : ~aar) & 0x01010101u;
            uint32_t eqe  = eqz4((s   & 0x0F0F0F0Fu) ^ erep);
            uint32_t eqer = eqz4((sar & 0x0F0F0F0Fu) ^ erep);
            uint32_t bbl = eqe  & ndgbl & ndg & mtc & gtb(d, dbl)  & gbl & g;
            uint32_t bar = eqer & ndgar & ndg & mta & gtb(dar, d)  & gar & g;
            nxt[i * RWS + jw] = s ^ ((s ^ sbl) & bmask(bbl)) ^ ((s ^ sar) & bmask(bar));
        }
        __syncthreads();
        uint32_t* t = cur; cur = nxt; nxt = t;
    }

    // ---- fused expansion: core 32x64 to 20 f32 channels ----
    float* ob = out + (size_t)b * NCH * PLANE;
    for (int idx = tid; idx < NCH * TILE_R * 16; idx += 256) {
        int col4 = idx & 15;
        int row  = (idx >> 4) & (TILE_R - 1);
        int c    = idx >> 9;                  // TILE_R*16 = 512 per channel
        uint32_t w = cur[(HALO_T + row) * RWS + (HALO_W / 4) + col4];
        float4 v;
        float* vv = &v.x;
#pragma unroll
        for (int q = 0; q < 4; ++q) {
            uint32_t byte = (w >> (8 * q)) & 0xFFu;
            float val;
            if (c < 14)       val = ((byte & 15u) == (uint32_t)c) ? 1.0f : 0.0f;
            else if (c == 14) val = (float)((byte >> 5) & 7u);
            else if (c == 15) val = (float)((byte >> 4) & 1u);
            else              val = 0.0f;
            vv[q] = val;
        }
        *(float4*)(ob + (size_t)c * PLANE + (size_t)(h0 + row) * WW + (w0 + col4 * 4)) = v;
    }
}

extern "C" void kernel_launch(void* const* d_in, const int* in_sizes, int n_in,
                              void* d_out, int out_size, void* d_ws, size_t ws_size,
                              hipStream_t stream) {
    const float* world = (const float*)d_in[0];
    const float* rnd   = (const float*)d_in[1];
    float* out = (float*)d_out;
    uint32_t* st = (uint32_t*)d_ws;   // 2 MB packed byte grid

    extract_k<<<2048, 256, 0, stream>>>(world, st);

    dim3 grid(WW / TILE_C, HH / TILE_R, 8);
    sim_k<<<grid, 256, 0, stream>>>((const uint8_t*)st, rnd, out);
}

// Round 5
// 58.361 us; speedup vs baseline: 1.2061x; 1.0777x over previous
//
#include <hip/hip_runtime.h>
#include <stdint.h>

#define HH 512
#define WW 512
#define PLANE (HH*WW)
#define NCH 20

// grav[] = {1,0,1,1,1,0,0,1,0,1,1,1,1,0}, 1 bit per element
#define GRAV_PACK 0x1E9Du

// ---------------- SWAR helpers (per-byte lanes) ----------------
__device__ __forceinline__ uint32_t eqz4(uint32_t x) {
    uint32_t nz = (x | (x >> 1) | (x >> 2) | (x >> 3)) & 0x01010101u;
    return nz ^ 0x01010101u;
}
__device__ __forceinline__ uint32_t gtb(uint32_t a, uint32_t b) {
    uint32_t t = (a | 0x08080808u) - b;
    return ((t + 0x07070707u) & 0x10101010u) >> 4;
}
__device__ __forceinline__ uint32_t bmask(uint32_t b) {
    uint32_t h = b << 7;
    return (h - (h >> 7)) | h;
}

// ---------------- Kernel 1: pack eid|grav<<4|dens<<5 (10-channel read) ----------------
__device__ __forceinline__ uint32_t pack_cell(float d_,
                                              float c1_, float c5_, float c6_, float c8_,
                                              float c2_, float c9_, float c10_,
                                              float c3_, float c4_) {
    int d = (int)d_;
    int e;
    if (d == 4)      e = (c1_ != 0.f) ? 1 : (c5_ != 0.f) ? 5 : (c6_ != 0.f) ? 6 : (c8_ != 0.f) ? 8 : 13;
    else if (d == 3) e = (c2_ != 0.f) ? 2 : (c9_ != 0.f) ? 9 : (c10_ != 0.f) ? 10 : 12;
    else if (d == 2) e = (c3_ != 0.f) ? 3 : 11;
    else if (d == 1) e = 0;
    else             e = (c4_ != 0.f) ? 4 : 7;
    int g = (int)((GRAV_PACK >> e) & 1u);
    return (uint32_t)(e | (g << 4) | (d << 5));
}

__global__ __launch_bounds__(256) void extract_k(const float* __restrict__ world,
                                                 uint32_t* __restrict__ st) {
    int idx = blockIdx.x * 256 + threadIdx.x;      // 4 cells each
    int b  = idx >> 16;
    int p4 = idx & 0xFFFF;
    const float4* base = (const float4*)(world + (size_t)b * NCH * PLANE) + p4;
    float4 vD  = base[14 * (PLANE / 4)];
    float4 v1  = base[ 1 * (PLANE / 4)];
    float4 v5  = base[ 5 * (PLANE / 4)];
    float4 v6  = base[ 6 * (PLANE / 4)];
    float4 v8  = base[ 8 * (PLANE / 4)];
    float4 v2  = base[ 2 * (PLANE / 4)];
    float4 v9  = base[ 9 * (PLANE / 4)];
    float4 v10 = base[10 * (PLANE / 4)];
    float4 v3  = base[ 3 * (PLANE / 4)];
    float4 v4  = base[ 4 * (PLANE / 4)];
    uint32_t b0 = pack_cell(vD.x, v1.x, v5.x, v6.x, v8.x, v2.x, v9.x, v10.x, v3.x, v4.x);
    uint32_t b1 = pack_cell(vD.y, v1.y, v5.y, v6.y, v8.y, v2.y, v9.y, v10.y, v3.y, v4.y);
    uint32_t b2 = pack_cell(vD.z, v1.z, v5.z, v6.z, v8.z, v2.z, v9.z, v10.z, v3.z, v4.z);
    uint32_t b3 = pack_cell(vD.w, v1.w, v5.w, v6.w, v8.w, v2.w, v9.w, v10.w, v3.w, v4.w);
    st[idx] = b0 | (b1 << 8) | (b2 << 16) | (b3 << 24);
}

// ---------------- Kernel 2: 2-tile pipelined SWAR sim + expansion ----------------
#define TILE_R 32
#define TILE_C 64
#define HALO_T 9
#define HALO_B 8
#define HALO_W 8                       // bytes; word-aligned halo
#define RH (TILE_R + HALO_T + HALO_B)  // 49 rows
#define RWW 20                         // words per row (80 bytes)
#define RWS 21                         // LDS row stride in words
#define NW (RH*RWW)                    // 980 words
#define NOWN 4                         // ceil(NW/256)

__global__ __launch_bounds__(256, 2) void sim_k(const uint8_t* __restrict__ st_in,
                                                const float* __restrict__ rnd,
                                                float* __restrict__ out) {
    __shared__ uint32_t bufA[RH * RWS];
    __shared__ uint32_t bufB[RH * RWS];
    __shared__ uint32_t aux [RH * RWS];   // per byte: bit0 fall_dir, bit1 did_gravity

    const int tid = threadIdx.x;
    const int h0  = blockIdx.y * TILE_R;
    const int w0  = blockIdx.x * TILE_C;

    uint32_t sreg[NOWN], freg[NOWN], dgreg[NOWN];

    // ---- helpers ----
    auto zero4 = [&](float* ob) {
        float4 z = {0.f, 0.f, 0.f, 0.f};
        for (int idx = tid; idx < 4 * TILE_R * 16; idx += 256) {
            int cw = idx & 15, row = (idx >> 4) & (TILE_R - 1), c = 16 + (idx >> 9);
            *(float4*)(ob + (size_t)c * PLANE + (size_t)(h0 + row) * WW + (w0 + cw * 4)) = z;
        }
    };

    auto stage = [&](const uint8_t* stb, const float* rb) {
#pragma unroll
        for (int k = 0; k < NOWN; ++k) {
            int r = tid + k * 256;
            if (r < NW) {
                int i = r / RWW, jw = r - i * RWW;
                int gh  = (h0 + i - HALO_T) & (HH - 1);
                int gwb = (w0 + jw * 4 - HALO_W) & (WW - 1);
                uint32_t w = *(const uint32_t*)(stb + gh * WW + gwb);
                bufA[i * RWS + jw] = w;
                sreg[k] = w;
                float4 rv = *(const float4*)(rb + gh * WW + gwb);
                uint32_t aw = 0;
                aw |= (rv.x > 0.5f) ? 0x00000001u : 0u;
                aw |= (rv.y > 0.5f) ? 0x00000100u : 0u;
                aw |= (rv.z > 0.5f) ? 0x00010000u : 0u;
                aw |= (rv.w > 0.5f) ? 0x01000000u : 0u;
                freg[k] = aw;
                dgreg[k] = 0u;
            }
        }
    };

    auto passes = [&]() {
        // pass 0: stone support / gravity rewrite (zero-padded at global edges)
#pragma unroll
        for (int k = 0; k < NOWN; ++k) {
            int r = tid + k * 256;
            if (r < NW) {
                int i = r / RWW, jw = r - i * RWW;
                uint32_t s = sreg[k];
                uint32_t stm = eqz4((s & 0x0F0F0F0Fu) ^ 0x09090909u);
                int im = (i > 0) ? i - 1 : 0;
                int jl = (jw > 0) ? jw - 1 : 0;
                int jr = (jw < RWW - 1) ? jw + 1 : RWW - 1;
                uint32_t wU  = bufA[im * RWS + jw];
                uint32_t wUL = bufA[im * RWS + jl];
                uint32_t wUR = bufA[im * RWS + jr];
                uint32_t upL = (wU << 8) | (wUL >> 24);
                uint32_t upR = (wU >> 8) | (wUR << 24);
                uint32_t stL = eqz4((upL & 0x0F0F0F0Fu) ^ 0x09090909u);
                uint32_t stR = eqz4((upR & 0x0F0F0F0Fu) ^ 0x09090909u);
                int gh  = (h0 + i - HALO_T) & (HH - 1);
                int gwb = (w0 + jw * 4 - HALO_W) & (WW - 1);
                uint32_t rowOK = (gh != 0) ? 0x01010101u : 0u;
                uint32_t okL = 0x01010101u ^ ((gwb == 0)      ? 0x00000001u : 0u);
                uint32_t okR = 0x01010101u ^ ((gwb == WW - 4) ? 0x01000000u : 0u);
                uint32_t supL = stL & okL & rowOK;
                uint32_t supR = stR & okR & rowOK;
                uint32_t g2 = 0x01010101u ^ (supL & supR);
                uint32_t ns = (s & ~0x10101010u) | (g2 << 4);
                uint32_t res = s ^ ((s ^ ns) & bmask(stm));
                bufB[i * RWS + jw] = res;
                sreg[k] = res;
            }
        }
        __syncthreads();

        uint32_t* cur = bufB;
        uint32_t* nxt = bufA;

        // passes 1..4: vertical gravity (did_gravity kept in registers)
        for (int curr = 0; curr < 4; ++curr) {
            const uint32_t crep = (uint32_t)curr * 0x01010101u;
#pragma unroll
            for (int k = 0; k < NOWN; ++k) {
                int r = tid + k * 256;
                if (r < NW) {
                    int i = r / RWW, jw = r - i * RWW;
                    int ia = (i > 0) ? i - 1 : 0;
                    int ib = (i < RH - 1) ? i + 1 : RH - 1;
                    uint32_t s  = sreg[k];
                    uint32_t sa = cur[ia * RWS + jw];
                    uint32_t sb = cur[ib * RWS + jw];
                    uint32_t d  = (s  >> 5) & 0x07070707u;
                    uint32_t da = (sa >> 5) & 0x07070707u;
                    uint32_t db = (sb >> 5) & 0x07070707u;
                    uint32_t g  = (s  >> 4) & 0x01010101u;
                    uint32_t ga = (sa >> 4) & 0x01010101u;
                    uint32_t gb = (sb >> 4) & 0x01010101u;
                    uint32_t bel = eqz4(d ^ crep)  & gtb(d, db) & gb & g;
                    uint32_t abv = eqz4(da ^ crep) & gtb(da, d) & ga & g;
                    uint32_t res = s ^ ((s ^ sb) & bmask(bel)) ^ ((s ^ sa) & bmask(abv));
                    nxt[i * RWS + jw] = res;
                    sreg[k] = res;
                    dgreg[k] |= abv;
                    if (curr == 3)   // merged aux write, covered by this pass's barrier
                        aux[i * RWS + jw] = freg[k] | (dgreg[k] << 1);
                }
            }
            __syncthreads();
            uint32_t* t = cur; cur = nxt; nxt = t;
        }

        // passes 5..8: diagonal falls (elem,dir) = (2,L),(2,R),(12,L),(12,R)
        for (int pass = 0; pass < 4; ++pass) {
            const int  elem = (pass < 2) ? 2 : 12;
            const bool fl   = ((pass & 1) == 0);
            const uint32_t erep = (uint32_t)elem * 0x01010101u;
#pragma unroll
            for (int k = 0; k < NOWN; ++k) {
                int r = tid + k * 256;
                if (r < NW) {
                    int i = r / RWW, jw = r - i * RWW;
                    int ia = (i > 0) ? i - 1 : 0;
                    int ib = (i < RH - 1) ? i + 1 : RH - 1;
                    int jl = (jw > 0) ? jw - 1 : 0;
                    int jr = (jw < RWW - 1) ? jw + 1 : RWW - 1;
                    uint32_t s  = sreg[k];
                    uint32_t wB = cur[ib * RWS + jw];
                    uint32_t wA = cur[ia * RWS + jw];
                    uint32_t aB = aux[ib * RWS + jw];
                    uint32_t aA = aux[ia * RWS + jw];
                    uint32_t sbl, sar, abl, aar;
                    if (fl) {
                        uint32_t wBL = cur[ib * RWS + jl], wAR = cur[ia * RWS + jr];
                        uint32_t aBL = aux[ib * RWS + jl], aAR = aux[ia * RWS + jr];
                        sbl = (wB << 8) | (wBL >> 24);
                        sar = (wA >> 8) | (wAR << 24);
                        abl = (aB << 8) | (aBL >> 24);
                        aar = (aA >> 8) | (aAR << 24);
                    } else {
                        uint32_t wBR = cur[ib * RWS + jr], wAL = cur[ia * RWS + jl];
                        uint32_t aBR = aux[ib * RWS + jr], aAL = aux[ia * RWS + jl];
                        sbl = (wB >> 8) | (wBR << 24);
                        sar = (wA << 8) | (wAL >> 24);
                        abl = (aB >> 8) | (aBR << 24);
                        aar = (aA << 8) | (aAL >> 24);
                    }
                    uint32_t d   = (s   >> 5) & 0x07070707u;
                    uint32_t dbl = (sbl >> 5) & 0x07070707u;
                    uint32_t dar = (sar >> 5) & 0x07070707u;
                    uint32_t g   = (s   >> 4) & 0x01010101u;
                    uint32_t gbl = (sbl >> 4) & 0x01010101u;
                    uint32_t gar = (sar >> 4) & 0x01010101u;
                    uint32_t ndg   = dgreg[k] ^ 0x01010101u;
                    uint32_t ndgbl = ((~abl) >> 1) & 0x01010101u;
                    uint32_t ndgar = ((~aar) >> 1) & 0x01010101u;
                    uint32_t mtc = (fl ? freg[k] : ~freg[k]) & 0x01010101u;
                    uint32_t mta = (fl ? aar : ~aar) & 0x01010101u;
                    uint32_t eqe  = eqz4((s   & 0x0F0F0F0Fu) ^ erep);
                    uint32_t eqer = eqz4((sar & 0x0F0F0F0Fu) ^ erep);
                    uint32_t bbl = eqe  & ndgbl & ndg & mtc & gtb(d, dbl) & gbl & g;
                    uint32_t bar = eqer & ndgar & ndg & mta & gtb(dar, d) & gar & g;
                    uint32_t res = s ^ ((s ^ sbl) & bmask(bbl)) ^ ((s ^ sar) & bmask(bar));
                    nxt[i * RWS + jw] = res;
                    sreg[k] = res;
                }
            }
            __syncthreads();
            uint32_t* t = cur; cur = nxt; nxt = t;
        }
        // final state is in bufB (9 passes: B,A,B,A,B,A,B,A,B)
    };

    auto expand = [&](float* ob) {   // reads bufB only
#pragma unroll
        for (int k = 0; k < 2; ++k) {
            int ci  = tid + k * 256;          // 0..511 core words
            int row = ci >> 4, cw = ci & 15;
            uint32_t w = bufB[(HALO_T + row) * RWS + (HALO_W / 4) + cw];
            float* base = ob + (size_t)(h0 + row) * WW + (w0 + cw * 4);
#pragma unroll
            for (int c = 0; c < 16; ++c) {
                float4 v;
                float* vv = &v.x;
#pragma unroll
                for (int q = 0; q < 4; ++q) {
                    uint32_t byte = (w >> (8 * q)) & 0xFFu;
                    float val;
                    if (c < 14)       val = ((byte & 15u) == (uint32_t)c) ? 1.0f : 0.0f;
                    else if (c == 14) val = (float)((byte >> 5) & 7u);
                    else              val = (float)((byte >> 4) & 1u);
                    vv[q] = val;
                }
                *(float4*)(base + (size_t)c * PLANE) = v;
            }
        }
    };

    // ---- 2-tile pipeline: batches z and z+4 ----
    const int bA = blockIdx.z, bB = blockIdx.z + 4;
    const uint8_t* stA = st_in + (size_t)bA * PLANE;
    const uint8_t* stB = st_in + (size_t)bB * PLANE;
    const float*   rA  = rnd   + (size_t)bA * PLANE;
    const float*   rB  = rnd   + (size_t)bB * PLANE;
    float* obA = out + (size_t)bA * NCH * PLANE;
    float* obB = out + (size_t)bB * NCH * PLANE;

    zero4(obA);                 // drains under tile-A passes
    stage(stA, rA);
    __syncthreads();
    passes();                   // tile A -> bufB

    zero4(obB);                 // drains under tile-B passes
    stage(stB, rB);             // writes bufA (free after pass 8); loads hide under expand
    expand(obA);                // reads bufB; stores drain under tile-B passes
    __syncthreads();
    passes();                   // tile B -> bufB
    expand(obB);
}

extern "C" void kernel_launch(void* const* d_in, const int* in_sizes, int n_in,
                              void* d_out, int out_size, void* d_ws, size_t ws_size,
                              hipStream_t stream) {
    const float* world = (const float*)d_in[0];
    const float* rnd   = (const float*)d_in[1];
    float* out = (float*)d_out;
    uint32_t* st = (uint32_t*)d_ws;   // 2 MB packed byte grid

    extract_k<<<2048, 256, 0, stream>>>(world, st);

    dim3 grid(WW / TILE_C, HH / TILE_R, 4);   // 512 blocks, 2 tiles each
    sim_k<<<grid, 256, 0, stream>>>((const uint8_t*)st, rnd, out);
}